// Round 21
// baseline (79.226 us; speedup 1.0000x reference)
//
#include <hip/hip_runtime.h>
#include <hip/hip_bf16.h>

// DeformableAttention: BS=4, Hq=Wq=64, C=256, M=8, K=4, L=4, CV=32
// SCALES = 64,32,16,8
//
// All-f16 pipeline, pre-transposed f16 weights, locality-optimized layouts:
//  D0 transpose_w: Wz,Wo,Wa,Wp,Wm (f32 [k][n]) -> f16 [n][k]
//  D1 gemm_z_wp : z = f16(q@Wz+bz)  AND  wp_l = f16(feat_l@Wp+bp)  (BM=64)
//  D2 gemm_zo_at: zo = f16(z@Wo+bo) with offset-channel permutation, AND
//                 za blocks: LDS-transpose + register-local softmax (BM=64)
//  D4 sample13  : block=(b,qx,ya) 512thr; wave=level, cluster=k; FULL 16-load
//                 tap hoist (max memory ILP); attn+ref staged in LDS;
//                 coalesced row stores
//  D5 gemm_final: out = out_pre@Wm+bm -> f32 (BM=64)
//
// GEMM staging: LDS tiles linear [rows][32] f16, 16B-quarter XOR swizzle
// phys_q = sem_q ^ (row&3); f16 operands via global_load_lds width=16
// (pre-swizzled global source, linear LDS dest); f32 A reg-staged.
//
// ws (MB): z/out_pre@0(8) zo@16(8) attn@24(4)
//   wp0@28(8) wp1@36(2) wp2@38(.5) wp3@38.5(.125)
//   Wzt@40 Woat@40.25 Wpt@40.75 Wmt@41. Peak ~41.25 MB.

typedef __attribute__((ext_vector_type(8))) _Float16 half8;
typedef __attribute__((ext_vector_type(2))) _Float16 half2t;
typedef __attribute__((ext_vector_type(4))) float f32x4;

#if __has_builtin(__builtin_amdgcn_fdot2)
__device__ __forceinline__ float fdot2f(half2t a, half2t b, float c) {
    return __builtin_amdgcn_fdot2(a, b, c, false);
}
#else
__device__ __forceinline__ float fdot2f(half2t a, half2t b, float c) {
    return c + (float)a.x * (float)b.x + (float)a.y * (float)b.y;
}
#endif

#define GLOAD_LDS16(gp, lp)                                                      \
    __builtin_amdgcn_global_load_lds(                                            \
        (const __attribute__((address_space(1))) void*)(gp),                     \
        (__attribute__((address_space(3))) void*)(lp), 16, 0, 0)

// f16-element offset of (row, semantic 8-elem quarter) in a [rows][32] tile
__device__ __forceinline__ int swz(int row, int sem_q) {
    return row * 32 + ((sem_q ^ (row & 3)) * 8);
}

// ---------------------------------------------------------------------------
// D0: transpose+convert weights. 64x64 tiles via LDS. 72 blocks.
// ---------------------------------------------------------------------------
__global__ __launch_bounds__(256) void transpose_w(
    const float* __restrict__ Wz, const float* __restrict__ Wo,
    const float* __restrict__ Wa, const float* __restrict__ Wp,
    const float* __restrict__ Wm,
    _Float16* __restrict__ Wzt, _Float16* __restrict__ Woat,
    _Float16* __restrict__ Wpt, _Float16* __restrict__ Wmt)
{
    __shared__ float ts[64][65];
    const int bid = blockIdx.x;
    const float* src; _Float16* dst; int N, tile;
    if      (bid < 16) { src = Wz; dst = Wzt;          N = 256; tile = bid; }
    else if (bid < 32) { src = Wo; dst = Woat;         N = 256; tile = bid - 16; }
    else if (bid < 40) { src = Wa; dst = Woat + 65536; N = 128; tile = bid - 32; }
    else if (bid < 56) { src = Wp; dst = Wpt;          N = 256; tile = bid - 40; }
    else               { src = Wm; dst = Wmt;          N = 256; tile = bid - 56; }
    const int ntn = N >> 6;
    const int k0 = (tile / ntn) * 64, n0 = (tile % ntn) * 64;
    const int t = threadIdx.x, tx = t & 63, ty = t >> 6;
    #pragma unroll
    for (int r = 0; r < 16; ++r) {
        const int kk = r * 4 + ty;
        ts[kk][tx] = src[(size_t)(k0 + kk) * N + n0 + tx];
    }
    __syncthreads();
    #pragma unroll
    for (int r = 0; r < 16; ++r) {
        const int nn = r * 4 + ty;
        dst[(size_t)(n0 + nn) * 256 + k0 + tx] = (_Float16)ts[tx][nn];
    }
}

// ---------------------------------------------------------------------------
// 64-row GEMM core (f32 A, reg-staged): acc[2][4] += A[64 @ m0] @ Bt[128 @ n0]^T
// ---------------------------------------------------------------------------
__device__ __forceinline__ void gemm_core64(
    _Float16* __restrict__ As, _Float16* __restrict__ Bs,
    const float* __restrict__ A, const _Float16* __restrict__ Bt,
    int m0, int n0, f32x4 (&acc)[2][4])
{
    const int t    = threadIdx.x;
    const int lane = t & 63, wid = t >> 6;
    const int wr = wid >> 1, wc = wid & 1;
    const int lr = lane & 15, sq = lane >> 4;
    const int grow = lane >> 2;
    const int gqs  = (lane & 3) ^ ((lane >> 2) & 3);

    const int arow = t >> 2, ac = t & 3;   // 64 rows x 4 quarters

    for (int kt = 0; kt < 256; kt += 32) {
        {
            const float* ap = A + (size_t)(m0 + arow) * 256 + kt + ac * 8;
            const float4 f0v = ((const float4*)ap)[0];
            const float4 f1v = ((const float4*)ap)[1];
            half8 h;
            h[0] = (_Float16)f0v.x; h[1] = (_Float16)f0v.y;
            h[2] = (_Float16)f0v.z; h[3] = (_Float16)f0v.w;
            h[4] = (_Float16)f1v.x; h[5] = (_Float16)f1v.y;
            h[6] = (_Float16)f1v.z; h[7] = (_Float16)f1v.w;
            *(half8*)&As[swz(arow, ac)] = h;
        }
        #pragma unroll
        for (int h = 0; h < 2; ++h) {
            const int rbase = wid * 32 + h * 16;
            const _Float16* gb = Bt + (size_t)(n0 + rbase + grow) * 256 + kt + gqs * 8;
            GLOAD_LDS16(gb, &Bs[rbase * 32]);
        }
        __syncthreads();

        half8 af[2], bf[4];
        #pragma unroll
        for (int m = 0; m < 2; ++m)
            af[m] = *(const half8*)&As[swz(wr*32 + m*16 + lr, sq)];
        #pragma unroll
        for (int n = 0; n < 4; ++n)
            bf[n] = *(const half8*)&Bs[swz(wc*64 + n*16 + lr, sq)];
        #pragma unroll
        for (int m = 0; m < 2; ++m)
            #pragma unroll
            for (int n = 0; n < 4; ++n)
                acc[m][n] = __builtin_amdgcn_mfma_f32_16x16x32_f16(af[m], bf[n], acc[m][n], 0, 0, 0);
        __syncthreads();
    }
}

// ---------------------------------------------------------------------------
// 64-row GEMM core (f16 A via gload): acc[2][4] += A[64 @ m0] @ Bt[128 @ n0]^T
// ---------------------------------------------------------------------------
__device__ __forceinline__ void gemm_core64f16(
    _Float16* __restrict__ As, _Float16* __restrict__ Bs,
    const _Float16* __restrict__ A, const _Float16* __restrict__ Bt,
    int m0, int n0, f32x4 (&acc)[2][4])
{
    const int t    = threadIdx.x;
    const int lane = t & 63, wid = t >> 6;
    const int wr = wid >> 1, wc = wid & 1;
    const int lr = lane & 15, sq = lane >> 4;
    const int grow = lane >> 2;
    const int gqs  = (lane & 3) ^ ((lane >> 2) & 3);

    for (int kt = 0; kt < 256; kt += 32) {
        {
            const int rbase = wid * 16;
            const _Float16* ga = A + (size_t)(m0 + rbase + grow) * 256 + kt + gqs * 8;
            GLOAD_LDS16(ga, &As[rbase * 32]);
        }
        #pragma unroll
        for (int h = 0; h < 2; ++h) {
            const int rbase = wid * 32 + h * 16;
            const _Float16* gb = Bt + (size_t)(n0 + rbase + grow) * 256 + kt + gqs * 8;
            GLOAD_LDS16(gb, &Bs[rbase * 32]);
        }
        __syncthreads();

        half8 af[2], bf[4];
        #pragma unroll
        for (int m = 0; m < 2; ++m)
            af[m] = *(const half8*)&As[swz(wr*32 + m*16 + lr, sq)];
        #pragma unroll
        for (int n = 0; n < 4; ++n)
            bf[n] = *(const half8*)&Bs[swz(wc*64 + n*16 + lr, sq)];
        #pragma unroll
        for (int m = 0; m < 2; ++m)
            #pragma unroll
            for (int n = 0; n < 4; ++n)
                acc[m][n] = __builtin_amdgcn_mfma_f32_16x16x32_f16(af[m], bf[n], acc[m][n], 0, 0, 0);
        __syncthreads();
    }
}

// f16 store epilogue, 64-row tile
__device__ __forceinline__ void epi64_f16(
    f32x4 (&acc)[2][4], const float* __restrict__ bias,
    _Float16* __restrict__ C, int N, int m0, int n0)
{
    const int t = threadIdx.x, lane = t & 63, wid = t >> 6;
    const int wr = wid >> 1, wc = wid & 1, lr = lane & 15;
    #pragma unroll
    for (int n = 0; n < 4; ++n) {
        const int col = n0 + wc*64 + n*16 + lr;
        const float bv = bias[col];
        #pragma unroll
        for (int m = 0; m < 2; ++m)
            #pragma unroll
            for (int r = 0; r < 4; ++r) {
                const int row = m0 + wr*32 + m*16 + (lane >> 4)*4 + r;
                C[(size_t)row * N + col] = (_Float16)(acc[m][n][r] + bv);
            }
    }
}

// wp store epilogue (plane layout), 64-row tile
__device__ __forceinline__ void epi64_wp(
    f32x4 (&acc)[2][4], const float* __restrict__ bias,
    _Float16* __restrict__ C, int m0, int n0, int shift)
{
    const int t = threadIdx.x, lane = t & 63, wid = t >> 6;
    const int wr = wid >> 1, wc = wid & 1, lr = lane & 15;
    const int mask = (1 << shift) - 1;
    #pragma unroll
    for (int n = 0; n < 4; ++n) {
        const int col = n0 + wc*64 + n*16 + lr;
        const float bv = bias[col];
        const int mh = col >> 5, cv = col & 31;
        #pragma unroll
        for (int m = 0; m < 2; ++m)
            #pragma unroll
            for (int r = 0; r < 4; ++r) {
                const int row = m0 + wr*32 + m*16 + (lane >> 4)*4 + r;
                const int bb = row >> shift, pix = row & mask;
                C[((((size_t)(bb * 8 + mh)) << shift) + pix) * 32 + cv] =
                    (_Float16)(acc[m][n][r] + bv);
            }
    }
}

// D1: z GEMM (by<256) + all 4 wp GEMMs (by>=256). BM=64 -> 1192 blocks.
__global__ __launch_bounds__(256) void gemm_z_wp(
    const float* __restrict__ q, const _Float16* __restrict__ Wzt,
    const float* __restrict__ bz, _Float16* __restrict__ z,
    const float* __restrict__ f0, const float* __restrict__ f1,
    const float* __restrict__ f2, const float* __restrict__ f3,
    const _Float16* __restrict__ Wpt, const float* __restrict__ bp,
    _Float16* __restrict__ w0, _Float16* __restrict__ w1,
    _Float16* __restrict__ w2, _Float16* __restrict__ w3)
{
    __shared__ _Float16 As[64 * 32];
    __shared__ _Float16 Bs[128 * 32];
    const int by = blockIdx.y, bx = blockIdx.x;
    f32x4 acc[2][4] = {};
    if (by < 256) {
        gemm_core64(As, Bs, q, Wzt, by * 64, bx * 128, acc);
        epi64_f16(acc, bz, z, 256, by * 64, bx * 128);
    } else {
        const int y = by - 256;
        const float* A; _Float16* C; int m0, shift;
        if      (y < 256) { A = f0; C = w0; m0 = y * 64;         shift = 12; }
        else if (y < 320) { A = f1; C = w1; m0 = (y - 256) * 64; shift = 10; }
        else if (y < 336) { A = f2; C = w2; m0 = (y - 320) * 64; shift = 8;  }
        else              { A = f3; C = w3; m0 = (y - 336) * 64; shift = 6;  }
        gemm_core64(As, Bs, A, Wpt, m0, bx * 128, acc);
        epi64_wp(acc, bp, C, m0, bx * 128, shift);
    }
}

// D2: zo GEMM with channel permutation (bx<2) + za GEMM with fused
// LDS-transpose softmax (bx==2). BM=64 -> 768 blocks. smax[64][136] overlay.
__global__ __launch_bounds__(256) void gemm_zo_at(
    const _Float16* __restrict__ z, const _Float16* __restrict__ Woat,
    const float* __restrict__ bo, const float* __restrict__ ba,
    _Float16* __restrict__ zo, _Float16* __restrict__ attn)
{
    __shared__ __align__(16) char ldsbuf[64 * 136 * 2];  // 17408B >= As+Bs 12288B
    _Float16* As = (_Float16*)ldsbuf;
    _Float16* Bs = As + 64 * 32;
    _Float16 (*smax)[136] = (_Float16(*)[136])ldsbuf;

    const int bx = blockIdx.x, by = blockIdx.y;
    const int m0 = by * 64;
    f32x4 acc[2][4] = {};
    gemm_core64f16(As, Bs, z, Woat, m0, bx * 128, acc);

    const int t = threadIdx.x, lane = t & 63, wid = t >> 6;
    const int wr = wid >> 1, wc = wid & 1, lr = lane & 15;

    if (bx < 2) {
        #pragma unroll
        for (int n = 0; n < 4; ++n) {
            const int c = bx * 128 + wc*64 + n*16 + lr;
            const float bv = bo[c];
            const int cp = (((c >> 3) & 3) << 6) | ((c >> 5) << 3)
                         | (((c >> 1) & 3) << 1) | (c & 1);
            #pragma unroll
            for (int m = 0; m < 2; ++m)
                #pragma unroll
                for (int r = 0; r < 4; ++r) {
                    const int row = m0 + wr*32 + m*16 + (lane >> 4)*4 + r;
                    zo[(size_t)row * 256 + cp] = (_Float16)(acc[m][n][r] + bv);
                }
        }
    } else {
        __syncthreads();  // all waves done with As/Bs before overlay
        #pragma unroll
        for (int n = 0; n < 4; ++n) {
            const int col = wc*64 + n*16 + lr;
            const float bv = ba[col];
            #pragma unroll
            for (int m = 0; m < 2; ++m)
                #pragma unroll
                for (int r = 0; r < 4; ++r) {
                    const int rowl = wr*32 + m*16 + (lane >> 4)*4 + r;
                    smax[rowl][col] = (_Float16)(acc[m][n][r] + bv);
                }
        }
        __syncthreads();
        #pragma unroll
        for (int j = 0; j < 2; ++j) {
            const int g    = j * 256 + t;           // 0..511
            const int rowl = g >> 3, mh = g & 7;
            const half8* sp = (const half8*)&smax[rowl][mh * 16];
            const half8 a = sp[0], bb8 = sp[1];
            float v[16];
            #pragma unroll
            for (int i = 0; i < 8; ++i) { v[i] = (float)a[i]; v[8+i] = (float)bb8[i]; }
            float mx = v[0];
            #pragma unroll
            for (int i = 1; i < 16; ++i) mx = fmaxf(mx, v[i]);
            float s = 0.f;
            #pragma unroll
            for (int i = 0; i < 16; ++i) { v[i] = expf(v[i] - mx); s += v[i]; }
            const float inv = 1.f / s;
            half8 o0, o1;
            #pragma unroll
            for (int i = 0; i < 8; ++i) { o0[i] = (_Float16)(v[i]*inv); o1[i] = (_Float16)(v[8+i]*inv); }
            const int row  = m0 + rowl;
            const int qpos = row & 4095, b = row >> 12;
            const int k = qpos >> 10, qx = (qpos >> 4) & 63, ya = qpos & 15;
            half8* op = (half8*)(attn +
                ((((((size_t)b * 64 + qx) * 16 + ya) * 8 + mh) * 4 + k) * 16));
            op[0] = o0; op[1] = o1;
        }
    }
}

// D4: sample13. Block = (b,qx,ya), 512 threads; t = l*128 + yb*32 + m*4 + k.
// attn (1KB) + ref (128B) staged in LDS; FULL 16-tap-load hoist (max ILP);
// coalesced row stores.
__global__ __launch_bounds__(512) void sample13(
    const _Float16* __restrict__ zo,    // f16 [b][qy][qx][perm 256]
    const _Float16* __restrict__ attn,  // f16 [b][qx][ya][m][k][16]
    const float* __restrict__ ref,      // f32 [BS][64][64][2]
    const _Float16* __restrict__ wp0, const _Float16* __restrict__ wp1,
    const _Float16* __restrict__ wp2, const _Float16* __restrict__ wp3,
    _Float16* __restrict__ outp)        // f16 [b][p][256]
{
    __shared__ unsigned srow[4 * 129];
    __shared__ uint4 sattn[64];          // 1KB: [m][k][half16B]
    __shared__ float2 sref[16];          // [rb][yb]

    const int bid = blockIdx.x;
    const int blk = (bid & 7) * 512 + (bid >> 3);
    const int qx = (blk >> 4) & 63;
    const int ya = blk & 15;
    const int b  = blk >> 10;

    const int t  = threadIdx.x;
    const int k  = t & 3;
    const int m  = (t >> 2) & 7;
    const int yb = (t >> 5) & 3;
    const int l  = t >> 7;

    // stage attn slice (64 uint4) and ref slice (16 float2) once
    if (t < 64) {
        const uint4* ab = (const uint4*)(attn +
            (((((size_t)b * 64 + qx) * 16 + ya) * 8) * 4 * 16));
        sattn[t] = ab[t];
    } else if (t < 80) {
        const int i  = t - 64;           // rb*4 + ybs
        const int rb = i >> 2, ybs = i & 3;
        sref[i] = *(const float2*)(ref +
            ((size_t)(rb * 4096) + (ya * 4 + ybs) * 64 + qx) * 2);
    }

    const int qy = ya * 4 + yb;
    const int query = b * 4096 + qy * 64 + qx;

    const int hw = 64 >> l;
    const int shift = 12 - 2 * l;
    const float fw = (float)hw;
    const _Float16* wp = (l == 0) ? wp0 : (l == 1) ? wp1 : (l == 2) ? wp2 : wp3;

    const unsigned off2 = *(const unsigned*)(zo + (size_t)query * 256 + (l * 64 + m * 8 + k * 2));
    const half2t offh = __builtin_bit_cast(half2t, off2);
    const float offx = (float)offh.x;
    const float offy = (float)offh.y;

    __syncthreads();
    const float2 rr = sref[(m & 3) * 4 + yb];

    const float px  = rr.x * (fw - 1.f) + offx;
    const float py  = rr.y * (fw - 1.f) + offy;
    const float gx  = 2.f * px / (fw - 1.f) - 1.f;
    const float gy  = 2.f * py / (fw - 1.f) - 1.f;
    const float xim = (gx + 1.f) * (fw * 0.5f) - 0.5f;
    const float yim = (gy + 1.f) * (fw * 0.5f) - 0.5f;

    const float x0f = floorf(xim), y0f = floorf(yim);
    const float wx1 = xim - x0f, wy1 = yim - y0f;
    const float wx0 = 1.f - wx1, wy0 = 1.f - wy1;
    const int ix0 = (int)x0f, iy0 = (int)y0f;

    const _Float16* plane = wp + ((((size_t)(b * 8 + m)) << shift) * 32);

    // ---- phase 1: issue ALL 16 tap loads (4 taps x 4 uint4) ----
    float wtv[4];
    uint4 u[4][4];
    #pragma unroll
    for (int tap = 0; tap < 4; ++tap) {
        int iy = iy0 + (tap >> 1);
        int ix = ix0 + (tap & 1);
        const bool ok = (iy >= 0) & (iy < hw) & (ix >= 0) & (ix < hw);
        float wt = ((tap >> 1) ? wy1 : wy0) * ((tap & 1) ? wx1 : wx0);
        wtv[tap] = ok ? wt : 0.f;
        iy = min(max(iy, 0), hw - 1);
        ix = min(max(ix, 0), hw - 1);
        const uint4* tp = (const uint4*)(plane + ((size_t)(iy * hw + ix)) * 32);
        u[tap][0] = tp[0]; u[tap][1] = tp[1]; u[tap][2] = tp[2]; u[tap][3] = tp[3];
    }

    // attn weights from LDS
    half2t w[8];
    {
        const uint4 wa = sattn[(m * 4 + k) * 2];
        const uint4 wb = sattn[(m * 4 + k) * 2 + 1];
        w[0] = __builtin_bit_cast(half2t, wa.x); w[1] = __builtin_bit_cast(half2t, wa.y);
        w[2] = __builtin_bit_cast(half2t, wa.z); w[3] = __builtin_bit_cast(half2t, wa.w);
        w[4] = __builtin_bit_cast(half2t, wb.x); w[5] = __builtin_bit_cast(half2t, wb.y);
        w[6] = __builtin_bit_cast(half2t, wb.z); w[7] = __builtin_bit_cast(half2t, wb.w);
    }

    // ---- phase 2: fdot2 chains ----
    float r0 = 0.f, r1 = 0.f;
    #pragma unroll
    for (int tap = 0; tap < 4; ++tap) {
        float d0 = 0.f, d1 = 0.f;
        d0 = fdot2f(__builtin_bit_cast(half2t, u[tap][0].x), w[0], d0);
        d0 = fdot2f(__builtin_bit_cast(half2t, u[tap][0].y), w[1], d0);
        d0 = fdot2f(__builtin_bit_cast(half2t, u[tap][0].z), w[2], d0);
        d0 = fdot2f(__builtin_bit_cast(half2t, u[tap][0].w), w[3], d0);
        d0 = fdot2f(__builtin_bit_cast(half2t, u[tap][1].x), w[4], d0);
        d0 = fdot2f(__builtin_bit_cast(half2t, u[tap][1].y), w[5], d0);
        d0 = fdot2f(__builtin_bit_cast(half2t, u[tap][1].z), w[6], d0);
        d0 = fdot2f(__builtin_bit_cast(half2t, u[tap][1].w), w[7], d0);
        d1 = fdot2f(__builtin_bit_cast(half2t, u[tap][2].x), w[0], d1);
        d1 = fdot2f(__builtin_bit_cast(half2t, u[tap][2].y), w[1], d1);
        d1 = fdot2f(__builtin_bit_cast(half2t, u[tap][2].z), w[2], d1);
        d1 = fdot2f(__builtin_bit_cast(half2t, u[tap][2].w), w[3], d1);
        d1 = fdot2f(__builtin_bit_cast(half2t, u[tap][3].x), w[4], d1);
        d1 = fdot2f(__builtin_bit_cast(half2t, u[tap][3].y), w[5], d1);
        d1 = fdot2f(__builtin_bit_cast(half2t, u[tap][3].z), w[6], d1);
        d1 = fdot2f(__builtin_bit_cast(half2t, u[tap][3].w), w[7], d1);
        r0 += wtv[tap] * d0;
        r1 += wtv[tap] * d1;
    }

    half2t pr; pr.x = (_Float16)r0; pr.y = (_Float16)r1;
    srow[k * 129 + (m * 16 + yb * 4 + l)] = __builtin_bit_cast(unsigned, pr);
    __syncthreads();

    {
        const int ro = t >> 7;
        const int e  = t & 127;
        const int prow = (ro << 10) | (qx << 4) | ya;
        ((unsigned*)(outp + ((size_t)b * 4096 + prow) * 256))[e] = srow[ro * 129 + e];
    }
}

// D5: final GEMM (f16 A, f32 out). BM=64 -> 512 blocks.
__global__ __launch_bounds__(256) void gemm_final(
    const _Float16* __restrict__ A, const _Float16* __restrict__ Wmt,
    const float* __restrict__ bias, float* __restrict__ C)
{
    __shared__ _Float16 As[64 * 32];
    __shared__ _Float16 Bs[128 * 32];
    const int m0 = blockIdx.y * 64, n0 = blockIdx.x * 128;
    f32x4 acc[2][4] = {};
    gemm_core64f16(As, Bs, A, Wmt, m0, n0, acc);
    const int t = threadIdx.x, lane = t & 63, wid = t >> 6;
    const int wr = wid >> 1, wc = wid & 1, lr = lane & 15;
    #pragma unroll
    for (int n = 0; n < 4; ++n) {
        const int col = n0 + wc*64 + n*16 + lr;
        const float bv = bias[col];
        #pragma unroll
        for (int m = 0; m < 2; ++m)
            #pragma unroll
            for (int r = 0; r < 4; ++r) {
                const int row = m0 + wr*32 + m*16 + (lane >> 4)*4 + r;
                C[(size_t)row * 256 + col] = acc[m][n][r] + bv;
            }
    }
}

extern "C" void kernel_launch(void* const* d_in, const int* in_sizes, int n_in,
                              void* d_out, int out_size, void* d_ws, size_t ws_size,
                              hipStream_t stream)
{
    const float* q   = (const float*)d_in[0];
    const float* ref = (const float*)d_in[1];
    const float* f0  = (const float*)d_in[2];
    const float* f1  = (const float*)d_in[3];
    const float* f2  = (const float*)d_in[4];
    const float* f3  = (const float*)d_in[5];
    const float* Wz  = (const float*)d_in[6];
    const float* bz  = (const float*)d_in[7];
    const float* Wo  = (const float*)d_in[8];
    const float* bo  = (const float*)d_in[9];
    const float* Wa  = (const float*)d_in[10];
    const float* ba  = (const float*)d_in[11];
    const float* Wp  = (const float*)d_in[12];
    const float* bp  = (const float*)d_in[13];
    const float* Wm  = (const float*)d_in[14];
    const float* bm  = (const float*)d_in[15];
    float* out = (float*)d_out;

    char* ws = (char*)d_ws;
    _Float16* z    = (_Float16*)(ws + ((size_t)0));          // f16 8MB
    _Float16* zo   = (_Float16*)(ws + ((size_t)16 << 20));   // f16 8MB
    _Float16* attn = (_Float16*)(ws + ((size_t)24 << 20));   // f16 4MB
    _Float16* wp0  = (_Float16*)(ws + ((size_t)28 << 20));   // f16 8MB
    _Float16* wp1  = (_Float16*)(ws + ((size_t)36 << 20));   // f16 2MB
    _Float16* wp2  = (_Float16*)(ws + ((size_t)38 << 20));   // f16 0.5MB
    _Float16* wp3  = (_Float16*)(ws + ((size_t)38 << 20) + ((size_t)512 << 10)); // 0.125MB
    _Float16* Wzt  = (_Float16*)(ws + ((size_t)40 << 20));                       // 128KB
    _Float16* Woat = (_Float16*)(ws + ((size_t)40 << 20) + ((size_t)256 << 10)); // 192KB
    _Float16* Wpt  = (_Float16*)(ws + ((size_t)40 << 20) + ((size_t)768 << 10)); // 128KB
    _Float16* Wmt  = (_Float16*)(ws + ((size_t)41 << 20));                       // 128KB
    _Float16* outp = z;  // f16 8MB, z dead after D2

    const dim3 blk(256);

    // D0: weights -> f16 transposed
    transpose_w<<<dim3(72), blk, 0, stream>>>(Wz, Wo, Wa, Wp, Wm, Wzt, Woat, Wpt, Wmt);
    // D1: z = f16(q@Wz+bz) AND wp_l = f16(feat_l@Wp+bp) (BM=64, plane layout)
    gemm_z_wp<<<dim3(2, 596), blk, 0, stream>>>(q, Wzt, bz, z,
                                                f0, f1, f2, f3, Wpt, bp,
                                                wp0, wp1, wp2, wp3);
    // D2: zo (permuted channels) AND attn (fused LDS softmax), BM=64
    gemm_zo_at<<<dim3(3, 256), blk, 0, stream>>>(z, Woat, bo, ba, zo, attn);
    // D4: sampling -> out_pre f16 (overwrites z region)
    sample13<<<dim3(4096), dim3(512), 0, stream>>>(zo, attn, ref, wp0, wp1, wp2, wp3, outp);
    // D5: out = out_pre@Wm+bm (BM=64)
    gemm_final<<<dim3(2, 256), blk, 0, stream>>>(outp, Wmt, bm, out);
}

// Round 22
// 76.511 us; speedup vs baseline: 1.0355x; 1.0355x over previous
//
#include <hip/hip_runtime.h>
#include <hip/hip_bf16.h>

// DeformableAttention: BS=4, Hq=Wq=64, C=256, M=8, K=4, L=4, CV=32
// SCALES = 64,32,16,8
//
// All-f16 pipeline, pre-transposed f16 weights, locality-optimized layouts:
//  D0 transpose_w: Wz,Wo,Wa,Wp,Wm (f32 [k][n]) -> f16 [n][k]
//  D1 gemm_z_wp : z = f16(q@Wz+bz)  AND  wp_l = f16(feat_l@Wp+bp)  (BM=64)
//  D2 gemm_zo_at: zo = f16(z@Wo+bo) with offset-channel permutation, AND
//                 za blocks: LDS-transpose + register-local softmax (BM=64)
//  D4 sample11  : block=(b,qx,ya) 512thr; wave=level, cluster=k; hoisted tap
//                 loads; block-shared attn slice in LDS (barrier AFTER tap
//                 issue -- staging overlaps the gather); coalesced row stores
//  D5 gemm_final: out = out_pre@Wm+bm -> f32 (BM=64)
//
// ALL GEMMs use BM=64 tiles: these 256-K GEMMs are occupancy/latency-bound
// (R14/R16/R17 evidence) -- more blocks beats bigger tiles every time.
//
// GEMM staging: LDS tiles linear [rows][32] f16, 16B-quarter XOR swizzle
// phys_q = sem_q ^ (row&3); f16 operands via global_load_lds width=16
// (pre-swizzled global source, linear LDS dest); f32 A reg-staged.
//
// ws (MB): z/out_pre@0(8) zo@16(8) attn@24(4)
//   wp0@28(8) wp1@36(2) wp2@38(.5) wp3@38.5(.125)
//   Wzt@40 Woat@40.25 Wpt@40.75 Wmt@41. Peak ~41.25 MB.

typedef __attribute__((ext_vector_type(8))) _Float16 half8;
typedef __attribute__((ext_vector_type(2))) _Float16 half2t;
typedef __attribute__((ext_vector_type(4))) float f32x4;

#if __has_builtin(__builtin_amdgcn_fdot2)
__device__ __forceinline__ float fdot2f(half2t a, half2t b, float c) {
    return __builtin_amdgcn_fdot2(a, b, c, false);
}
#else
__device__ __forceinline__ float fdot2f(half2t a, half2t b, float c) {
    return c + (float)a.x * (float)b.x + (float)a.y * (float)b.y;
}
#endif

#define GLOAD_LDS16(gp, lp)                                                      \
    __builtin_amdgcn_global_load_lds(                                            \
        (const __attribute__((address_space(1))) void*)(gp),                     \
        (__attribute__((address_space(3))) void*)(lp), 16, 0, 0)

// f16-element offset of (row, semantic 8-elem quarter) in a [rows][32] tile
__device__ __forceinline__ int swz(int row, int sem_q) {
    return row * 32 + ((sem_q ^ (row & 3)) * 8);
}

// ---------------------------------------------------------------------------
// D0: transpose+convert weights. 64x64 tiles via LDS. 72 blocks.
// ---------------------------------------------------------------------------
__global__ __launch_bounds__(256) void transpose_w(
    const float* __restrict__ Wz, const float* __restrict__ Wo,
    const float* __restrict__ Wa, const float* __restrict__ Wp,
    const float* __restrict__ Wm,
    _Float16* __restrict__ Wzt, _Float16* __restrict__ Woat,
    _Float16* __restrict__ Wpt, _Float16* __restrict__ Wmt)
{
    __shared__ float ts[64][65];
    const int bid = blockIdx.x;
    const float* src; _Float16* dst; int N, tile;
    if      (bid < 16) { src = Wz; dst = Wzt;          N = 256; tile = bid; }
    else if (bid < 32) { src = Wo; dst = Woat;         N = 256; tile = bid - 16; }
    else if (bid < 40) { src = Wa; dst = Woat + 65536; N = 128; tile = bid - 32; }
    else if (bid < 56) { src = Wp; dst = Wpt;          N = 256; tile = bid - 40; }
    else               { src = Wm; dst = Wmt;          N = 256; tile = bid - 56; }
    const int ntn = N >> 6;
    const int k0 = (tile / ntn) * 64, n0 = (tile % ntn) * 64;
    const int t = threadIdx.x, tx = t & 63, ty = t >> 6;
    #pragma unroll
    for (int r = 0; r < 16; ++r) {
        const int kk = r * 4 + ty;
        ts[kk][tx] = src[(size_t)(k0 + kk) * N + n0 + tx];
    }
    __syncthreads();
    #pragma unroll
    for (int r = 0; r < 16; ++r) {
        const int nn = r * 4 + ty;
        dst[(size_t)(n0 + nn) * 256 + k0 + tx] = (_Float16)ts[tx][nn];
    }
}

// ---------------------------------------------------------------------------
// 64-row GEMM core (f32 A, reg-staged): acc[2][4] += A[64 @ m0] @ Bt[128 @ n0]^T
// ---------------------------------------------------------------------------
__device__ __forceinline__ void gemm_core64(
    _Float16* __restrict__ As, _Float16* __restrict__ Bs,
    const float* __restrict__ A, const _Float16* __restrict__ Bt,
    int m0, int n0, f32x4 (&acc)[2][4])
{
    const int t    = threadIdx.x;
    const int lane = t & 63, wid = t >> 6;
    const int wr = wid >> 1, wc = wid & 1;
    const int lr = lane & 15, sq = lane >> 4;
    const int grow = lane >> 2;
    const int gqs  = (lane & 3) ^ ((lane >> 2) & 3);

    const int arow = t >> 2, ac = t & 3;   // 64 rows x 4 quarters

    for (int kt = 0; kt < 256; kt += 32) {
        {
            const float* ap = A + (size_t)(m0 + arow) * 256 + kt + ac * 8;
            const float4 f0v = ((const float4*)ap)[0];
            const float4 f1v = ((const float4*)ap)[1];
            half8 h;
            h[0] = (_Float16)f0v.x; h[1] = (_Float16)f0v.y;
            h[2] = (_Float16)f0v.z; h[3] = (_Float16)f0v.w;
            h[4] = (_Float16)f1v.x; h[5] = (_Float16)f1v.y;
            h[6] = (_Float16)f1v.z; h[7] = (_Float16)f1v.w;
            *(half8*)&As[swz(arow, ac)] = h;
        }
        #pragma unroll
        for (int h = 0; h < 2; ++h) {
            const int rbase = wid * 32 + h * 16;
            const _Float16* gb = Bt + (size_t)(n0 + rbase + grow) * 256 + kt + gqs * 8;
            GLOAD_LDS16(gb, &Bs[rbase * 32]);
        }
        __syncthreads();

        half8 af[2], bf[4];
        #pragma unroll
        for (int m = 0; m < 2; ++m)
            af[m] = *(const half8*)&As[swz(wr*32 + m*16 + lr, sq)];
        #pragma unroll
        for (int n = 0; n < 4; ++n)
            bf[n] = *(const half8*)&Bs[swz(wc*64 + n*16 + lr, sq)];
        #pragma unroll
        for (int m = 0; m < 2; ++m)
            #pragma unroll
            for (int n = 0; n < 4; ++n)
                acc[m][n] = __builtin_amdgcn_mfma_f32_16x16x32_f16(af[m], bf[n], acc[m][n], 0, 0, 0);
        __syncthreads();
    }
}

// ---------------------------------------------------------------------------
// 64-row GEMM core (f16 A via gload): acc[2][4] += A[64 @ m0] @ Bt[128 @ n0]^T
// ---------------------------------------------------------------------------
__device__ __forceinline__ void gemm_core64f16(
    _Float16* __restrict__ As, _Float16* __restrict__ Bs,
    const _Float16* __restrict__ A, const _Float16* __restrict__ Bt,
    int m0, int n0, f32x4 (&acc)[2][4])
{
    const int t    = threadIdx.x;
    const int lane = t & 63, wid = t >> 6;
    const int wr = wid >> 1, wc = wid & 1;
    const int lr = lane & 15, sq = lane >> 4;
    const int grow = lane >> 2;
    const int gqs  = (lane & 3) ^ ((lane >> 2) & 3);

    for (int kt = 0; kt < 256; kt += 32) {
        {
            const int rbase = wid * 16;
            const _Float16* ga = A + (size_t)(m0 + rbase + grow) * 256 + kt + gqs * 8;
            GLOAD_LDS16(ga, &As[rbase * 32]);
        }
        #pragma unroll
        for (int h = 0; h < 2; ++h) {
            const int rbase = wid * 32 + h * 16;
            const _Float16* gb = Bt + (size_t)(n0 + rbase + grow) * 256 + kt + gqs * 8;
            GLOAD_LDS16(gb, &Bs[rbase * 32]);
        }
        __syncthreads();

        half8 af[2], bf[4];
        #pragma unroll
        for (int m = 0; m < 2; ++m)
            af[m] = *(const half8*)&As[swz(wr*32 + m*16 + lr, sq)];
        #pragma unroll
        for (int n = 0; n < 4; ++n)
            bf[n] = *(const half8*)&Bs[swz(wc*64 + n*16 + lr, sq)];
        #pragma unroll
        for (int m = 0; m < 2; ++m)
            #pragma unroll
            for (int n = 0; n < 4; ++n)
                acc[m][n] = __builtin_amdgcn_mfma_f32_16x16x32_f16(af[m], bf[n], acc[m][n], 0, 0, 0);
        __syncthreads();
    }
}

// f16 store epilogue, 64-row tile
__device__ __forceinline__ void epi64_f16(
    f32x4 (&acc)[2][4], const float* __restrict__ bias,
    _Float16* __restrict__ C, int N, int m0, int n0)
{
    const int t = threadIdx.x, lane = t & 63, wid = t >> 6;
    const int wr = wid >> 1, wc = wid & 1, lr = lane & 15;
    #pragma unroll
    for (int n = 0; n < 4; ++n) {
        const int col = n0 + wc*64 + n*16 + lr;
        const float bv = bias[col];
        #pragma unroll
        for (int m = 0; m < 2; ++m)
            #pragma unroll
            for (int r = 0; r < 4; ++r) {
                const int row = m0 + wr*32 + m*16 + (lane >> 4)*4 + r;
                C[(size_t)row * N + col] = (_Float16)(acc[m][n][r] + bv);
            }
    }
}

// wp store epilogue (plane layout), 64-row tile
__device__ __forceinline__ void epi64_wp(
    f32x4 (&acc)[2][4], const float* __restrict__ bias,
    _Float16* __restrict__ C, int m0, int n0, int shift)
{
    const int t = threadIdx.x, lane = t & 63, wid = t >> 6;
    const int wr = wid >> 1, wc = wid & 1, lr = lane & 15;
    const int mask = (1 << shift) - 1;
    #pragma unroll
    for (int n = 0; n < 4; ++n) {
        const int col = n0 + wc*64 + n*16 + lr;
        const float bv = bias[col];
        const int mh = col >> 5, cv = col & 31;
        #pragma unroll
        for (int m = 0; m < 2; ++m)
            #pragma unroll
            for (int r = 0; r < 4; ++r) {
                const int row = m0 + wr*32 + m*16 + (lane >> 4)*4 + r;
                const int bb = row >> shift, pix = row & mask;
                C[((((size_t)(bb * 8 + mh)) << shift) + pix) * 32 + cv] =
                    (_Float16)(acc[m][n][r] + bv);
            }
    }
}

// D1: z GEMM (by<256) + all 4 wp GEMMs (by>=256). BM=64 -> 1192 blocks.
__global__ __launch_bounds__(256) void gemm_z_wp(
    const float* __restrict__ q, const _Float16* __restrict__ Wzt,
    const float* __restrict__ bz, _Float16* __restrict__ z,
    const float* __restrict__ f0, const float* __restrict__ f1,
    const float* __restrict__ f2, const float* __restrict__ f3,
    const _Float16* __restrict__ Wpt, const float* __restrict__ bp,
    _Float16* __restrict__ w0, _Float16* __restrict__ w1,
    _Float16* __restrict__ w2, _Float16* __restrict__ w3)
{
    __shared__ _Float16 As[64 * 32];
    __shared__ _Float16 Bs[128 * 32];
    const int by = blockIdx.y, bx = blockIdx.x;
    f32x4 acc[2][4] = {};
    if (by < 256) {
        gemm_core64(As, Bs, q, Wzt, by * 64, bx * 128, acc);
        epi64_f16(acc, bz, z, 256, by * 64, bx * 128);
    } else {
        const int y = by - 256;
        const float* A; _Float16* C; int m0, shift;
        if      (y < 256) { A = f0; C = w0; m0 = y * 64;         shift = 12; }
        else if (y < 320) { A = f1; C = w1; m0 = (y - 256) * 64; shift = 10; }
        else if (y < 336) { A = f2; C = w2; m0 = (y - 320) * 64; shift = 8;  }
        else              { A = f3; C = w3; m0 = (y - 336) * 64; shift = 6;  }
        gemm_core64(As, Bs, A, Wpt, m0, bx * 128, acc);
        epi64_wp(acc, bp, C, m0, bx * 128, shift);
    }
}

// D2: zo GEMM with channel permutation (bx<2) + za GEMM with fused
// LDS-transpose softmax (bx==2). BM=64 -> 768 blocks. smax[64][136] overlay.
__global__ __launch_bounds__(256) void gemm_zo_at(
    const _Float16* __restrict__ z, const _Float16* __restrict__ Woat,
    const float* __restrict__ bo, const float* __restrict__ ba,
    _Float16* __restrict__ zo, _Float16* __restrict__ attn)
{
    __shared__ __align__(16) char ldsbuf[64 * 136 * 2];  // 17408B >= As+Bs 12288B
    _Float16* As = (_Float16*)ldsbuf;
    _Float16* Bs = As + 64 * 32;
    _Float16 (*smax)[136] = (_Float16(*)[136])ldsbuf;

    const int bx = blockIdx.x, by = blockIdx.y;
    const int m0 = by * 64;
    f32x4 acc[2][4] = {};
    gemm_core64f16(As, Bs, z, Woat, m0, bx * 128, acc);

    const int t = threadIdx.x, lane = t & 63, wid = t >> 6;
    const int wr = wid >> 1, wc = wid & 1, lr = lane & 15;

    if (bx < 2) {
        #pragma unroll
        for (int n = 0; n < 4; ++n) {
            const int c = bx * 128 + wc*64 + n*16 + lr;
            const float bv = bo[c];
            const int cp = (((c >> 3) & 3) << 6) | ((c >> 5) << 3)
                         | (((c >> 1) & 3) << 1) | (c & 1);
            #pragma unroll
            for (int m = 0; m < 2; ++m)
                #pragma unroll
                for (int r = 0; r < 4; ++r) {
                    const int row = m0 + wr*32 + m*16 + (lane >> 4)*4 + r;
                    zo[(size_t)row * 256 + cp] = (_Float16)(acc[m][n][r] + bv);
                }
        }
    } else {
        __syncthreads();  // all waves done with As/Bs before overlay
        #pragma unroll
        for (int n = 0; n < 4; ++n) {
            const int col = wc*64 + n*16 + lr;
            const float bv = ba[col];
            #pragma unroll
            for (int m = 0; m < 2; ++m)
                #pragma unroll
                for (int r = 0; r < 4; ++r) {
                    const int rowl = wr*32 + m*16 + (lane >> 4)*4 + r;
                    smax[rowl][col] = (_Float16)(acc[m][n][r] + bv);
                }
        }
        __syncthreads();
        #pragma unroll
        for (int j = 0; j < 2; ++j) {
            const int g    = j * 256 + t;           // 0..511
            const int rowl = g >> 3, mh = g & 7;
            const half8* sp = (const half8*)&smax[rowl][mh * 16];
            const half8 a = sp[0], bb8 = sp[1];
            float v[16];
            #pragma unroll
            for (int i = 0; i < 8; ++i) { v[i] = (float)a[i]; v[8+i] = (float)bb8[i]; }
            float mx = v[0];
            #pragma unroll
            for (int i = 1; i < 16; ++i) mx = fmaxf(mx, v[i]);
            float s = 0.f;
            #pragma unroll
            for (int i = 0; i < 16; ++i) { v[i] = expf(v[i] - mx); s += v[i]; }
            const float inv = 1.f / s;
            half8 o0, o1;
            #pragma unroll
            for (int i = 0; i < 8; ++i) { o0[i] = (_Float16)(v[i]*inv); o1[i] = (_Float16)(v[8+i]*inv); }
            const int row  = m0 + rowl;
            const int qpos = row & 4095, b = row >> 12;
            const int k = qpos >> 10, qx = (qpos >> 4) & 63, ya = qpos & 15;
            half8* op = (half8*)(attn +
                ((((((size_t)b * 64 + qx) * 16 + ya) * 8 + mh) * 4 + k) * 16));
            op[0] = o0; op[1] = o1;
        }
    }
}

// D4: sample11. Block = (b,qx,ya), 512 threads; t = l*128 + yb*32 + m*4 + k.
// Block's 1KB attn slice staged ONCE into LDS; barrier sits AFTER the 16
// hoisted tap loads so staging latency overlaps the gather.
__global__ __launch_bounds__(512) void sample11(
    const _Float16* __restrict__ zo,    // f16 [b][qy][qx][perm 256]
    const _Float16* __restrict__ attn,  // f16 [b][qx][ya][m][k][16]
    const float* __restrict__ ref,      // f32 [BS][64][64][2]
    const _Float16* __restrict__ wp0, const _Float16* __restrict__ wp1,
    const _Float16* __restrict__ wp2, const _Float16* __restrict__ wp3,
    _Float16* __restrict__ outp)        // f16 [b][p][256]
{
    __shared__ unsigned srow[4 * 129];
    __shared__ uint4 sattn[64];          // 1KB: [m][k][half16B]

    const int bid = blockIdx.x;
    const int blk = (bid & 7) * 512 + (bid >> 3);
    const int qx = (blk >> 4) & 63;
    const int ya = blk & 15;
    const int b  = blk >> 10;

    const int t  = threadIdx.x;
    const int k  = t & 3;
    const int m  = (t >> 2) & 7;
    const int yb = (t >> 5) & 3;
    const int l  = t >> 7;

    // stage the block's attn slice (8 m x 4 k x 16 f16 = 64 uint4) once
    if (t < 64) {
        const uint4* ab = (const uint4*)(attn +
            (((((size_t)b * 64 + qx) * 16 + ya) * 8) * 4 * 16));
        sattn[t] = ab[t];
    }

    const int qy = ya * 4 + yb;
    const int query = b * 4096 + qy * 64 + qx;

    const int hw = 64 >> l;
    const int shift = 12 - 2 * l;
    const float fw = (float)hw;
    const _Float16* wp = (l == 0) ? wp0 : (l == 1) ? wp1 : (l == 2) ? wp2 : wp3;

    const unsigned off2 = *(const unsigned*)(zo + (size_t)query * 256 + (l * 64 + m * 8 + k * 2));
    const half2t offh = __builtin_bit_cast(half2t, off2);
    const float offx = (float)offh.x;
    const float offy = (float)offh.y;

    const int rb = m & 3;
    const float2 rr = *(const float2*)(ref + ((size_t)(rb * 4096) + qy * 64 + qx) * 2);

    const float px  = rr.x * (fw - 1.f) + offx;
    const float py  = rr.y * (fw - 1.f) + offy;
    const float gx  = 2.f * px / (fw - 1.f) - 1.f;
    const float gy  = 2.f * py / (fw - 1.f) - 1.f;
    const float xim = (gx + 1.f) * (fw * 0.5f) - 0.5f;
    const float yim = (gy + 1.f) * (fw * 0.5f) - 0.5f;

    const float x0f = floorf(xim), y0f = floorf(yim);
    const float wx1 = xim - x0f, wy1 = yim - y0f;
    const float wx0 = 1.f - wx1, wy0 = 1.f - wy1;
    const int ix0 = (int)x0f, iy0 = (int)y0f;

    const _Float16* plane = wp + ((((size_t)(b * 8 + m)) << shift) * 32);

    // issue all 16 tap loads (4 taps x 4 uint4)
    float wtv[4];
    uint4 u[4][4];
    #pragma unroll
    for (int tap = 0; tap < 4; ++tap) {
        int iy = iy0 + (tap >> 1);
        int ix = ix0 + (tap & 1);
        const bool ok = (iy >= 0) & (iy < hw) & (ix >= 0) & (ix < hw);
        float wt = ((tap >> 1) ? wy1 : wy0) * ((tap & 1) ? wx1 : wx0);
        wtv[tap] = ok ? wt : 0.f;
        iy = min(max(iy, 0), hw - 1);
        ix = min(max(ix, 0), hw - 1);
        const uint4* tp = (const uint4*)(plane + ((size_t)(iy * hw + ix)) * 32);
        u[tap][0] = tp[0]; u[tap][1] = tp[1]; u[tap][2] = tp[2]; u[tap][3] = tp[3];
    }

    // attn weights from LDS (barrier after tap issue)
    __syncthreads();
    half2t w[8];
    {
        const uint4 wa = sattn[(m * 4 + k) * 2];
        const uint4 wb = sattn[(m * 4 + k) * 2 + 1];
        w[0] = __builtin_bit_cast(half2t, wa.x); w[1] = __builtin_bit_cast(half2t, wa.y);
        w[2] = __builtin_bit_cast(half2t, wa.z); w[3] = __builtin_bit_cast(half2t, wa.w);
        w[4] = __builtin_bit_cast(half2t, wb.x); w[5] = __builtin_bit_cast(half2t, wb.y);
        w[6] = __builtin_bit_cast(half2t, wb.z); w[7] = __builtin_bit_cast(half2t, wb.w);
    }

    float r0 = 0.f, r1 = 0.f;
    #pragma unroll
    for (int tap = 0; tap < 4; ++tap) {
        float d0 = 0.f, d1 = 0.f;
        d0 = fdot2f(__builtin_bit_cast(half2t, u[tap][0].x), w[0], d0);
        d0 = fdot2f(__builtin_bit_cast(half2t, u[tap][0].y), w[1], d0);
        d0 = fdot2f(__builtin_bit_cast(half2t, u[tap][0].z), w[2], d0);
        d0 = fdot2f(__builtin_bit_cast(half2t, u[tap][0].w), w[3], d0);
        d0 = fdot2f(__builtin_bit_cast(half2t, u[tap][1].x), w[4], d0);
        d0 = fdot2f(__builtin_bit_cast(half2t, u[tap][1].y), w[5], d0);
        d0 = fdot2f(__builtin_bit_cast(half2t, u[tap][1].z), w[6], d0);
        d0 = fdot2f(__builtin_bit_cast(half2t, u[tap][1].w), w[7], d0);
        d1 = fdot2f(__builtin_bit_cast(half2t, u[tap][2].x), w[0], d1);
        d1 = fdot2f(__builtin_bit_cast(half2t, u[tap][2].y), w[1], d1);
        d1 = fdot2f(__builtin_bit_cast(half2t, u[tap][2].z), w[2], d1);
        d1 = fdot2f(__builtin_bit_cast(half2t, u[tap][2].w), w[3], d1);
        d1 = fdot2f(__builtin_bit_cast(half2t, u[tap][3].x), w[4], d1);
        d1 = fdot2f(__builtin_bit_cast(half2t, u[tap][3].y), w[5], d1);
        d1 = fdot2f(__builtin_bit_cast(half2t, u[tap][3].z), w[6], d1);
        d1 = fdot2f(__builtin_bit_cast(half2t, u[tap][3].w), w[7], d1);
        r0 += wtv[tap] * d0;
        r1 += wtv[tap] * d1;
    }

    half2t pr; pr.x = (_Float16)r0; pr.y = (_Float16)r1;
    srow[k * 129 + (m * 16 + yb * 4 + l)] = __builtin_bit_cast(unsigned, pr);
    __syncthreads();

    {
        const int ro = t >> 7;
        const int e  = t & 127;
        const int prow = (ro << 10) | (qx << 4) | ya;
        ((unsigned*)(outp + ((size_t)b * 4096 + prow) * 256))[e] = srow[ro * 129 + e];
    }
}

// D5: final GEMM (f16 A, f32 out). BM=64 -> 512 blocks.
__global__ __launch_bounds__(256) void gemm_final(
    const _Float16* __restrict__ A, const _Float16* __restrict__ Wmt,
    const float* __restrict__ bias, float* __restrict__ C)
{
    __shared__ _Float16 As[64 * 32];
    __shared__ _Float16 Bs[128 * 32];
    const int m0 = blockIdx.y * 64, n0 = blockIdx.x * 128;
    f32x4 acc[2][4] = {};
    gemm_core64f16(As, Bs, A, Wmt, m0, n0, acc);
    const int t = threadIdx.x, lane = t & 63, wid = t >> 6;
    const int wr = wid >> 1, wc = wid & 1, lr = lane & 15;
    #pragma unroll
    for (int n = 0; n < 4; ++n) {
        const int col = n0 + wc*64 + n*16 + lr;
        const float bv = bias[col];
        #pragma unroll
        for (int m = 0; m < 2; ++m)
            #pragma unroll
            for (int r = 0; r < 4; ++r) {
                const int row = m0 + wr*32 + m*16 + (lane >> 4)*4 + r;
                C[(size_t)row * 256 + col] = acc[m][n][r] + bv;
            }
    }
}

extern "C" void kernel_launch(void* const* d_in, const int* in_sizes, int n_in,
                              void* d_out, int out_size, void* d_ws, size_t ws_size,
                              hipStream_t stream)
{
    const float* q   = (const float*)d_in[0];
    const float* ref = (const float*)d_in[1];
    const float* f0  = (const float*)d_in[2];
    const float* f1  = (const float*)d_in[3];
    const float* f2  = (const float*)d_in[4];
    const float* f3  = (const float*)d_in[5];
    const float* Wz  = (const float*)d_in[6];
    const float* bz  = (const float*)d_in[7];
    const float* Wo  = (const float*)d_in[8];
    const float* bo  = (const float*)d_in[9];
    const float* Wa  = (const float*)d_in[10];
    const float* ba  = (const float*)d_in[11];
    const float* Wp  = (const float*)d_in[12];
    const float* bp  = (const float*)d_in[13];
    const float* Wm  = (const float*)d_in[14];
    const float* bm  = (const float*)d_in[15];
    float* out = (float*)d_out;

    char* ws = (char*)d_ws;
    _Float16* z    = (_Float16*)(ws + ((size_t)0));          // f16 8MB
    _Float16* zo   = (_Float16*)(ws + ((size_t)16 << 20));   // f16 8MB
    _Float16* attn = (_Float16*)(ws + ((size_t)24 << 20));   // f16 4MB
    _Float16* wp0  = (_Float16*)(ws + ((size_t)28 << 20));   // f16 8MB
    _Float16* wp1  = (_Float16*)(ws + ((size_t)36 << 20));   // f16 2MB
    _Float16* wp2  = (_Float16*)(ws + ((size_t)38 << 20));   // f16 0.5MB
    _Float16* wp3  = (_Float16*)(ws + ((size_t)38 << 20) + ((size_t)512 << 10)); // 0.125MB
    _Float16* Wzt  = (_Float16*)(ws + ((size_t)40 << 20));                       // 128KB
    _Float16* Woat = (_Float16*)(ws + ((size_t)40 << 20) + ((size_t)256 << 10)); // 192KB
    _Float16* Wpt  = (_Float16*)(ws + ((size_t)40 << 20) + ((size_t)768 << 10)); // 128KB
    _Float16* Wmt  = (_Float16*)(ws + ((size_t)41 << 20));                       // 128KB
    _Float16* outp = z;  // f16 8MB, z dead after D2

    const dim3 blk(256);

    // D0: weights -> f16 transposed
    transpose_w<<<dim3(72), blk, 0, stream>>>(Wz, Wo, Wa, Wp, Wm, Wzt, Woat, Wpt, Wmt);
    // D1: z = f16(q@Wz+bz) AND wp_l = f16(feat_l@Wp+bp) (BM=64, plane layout)
    gemm_z_wp<<<dim3(2, 596), blk, 0, stream>>>(q, Wzt, bz, z,
                                                f0, f1, f2, f3, Wpt, bp,
                                                wp0, wp1, wp2, wp3);
    // D2: zo (permuted channels) AND attn (fused LDS softmax), BM=64
    gemm_zo_at<<<dim3(3, 256), blk, 0, stream>>>(z, Woat, bo, ba, zo, attn);
    // D4: sampling -> out_pre f16 (overwrites z region)
    sample11<<<dim3(4096), dim3(512), 0, stream>>>(zo, attn, ref, wp0, wp1, wp2, wp3, outp);
    // D5: out = out_pre@Wm+bm (BM=64)
    gemm_final<<<dim3(2, 256), blk, 0, stream>>>(outp, Wmt, bm, out);
}